// Round 18
// baseline (541.432 us; speedup 1.0000x reference)
//
#include <hip/hip_runtime.h>
#include <hip/hip_bf16.h>

// Problem dims
#define V_    10000
#define ENC_  2048
#define D_    512
#define B_    128
#define L_    64
#define T_    63          // L-1 timesteps
#define M_    (B_ * L_ - B_)   // 8064 rows
#define G_    (3 * D_)    // 1536 gate width
#define LOGITS_SZ ((long)M_ * V_)   // 80,640,000
// fused kernel block roles
#define NB_SCAN 64
#define NB_GI   756       // 63 t-tiles x 12 n-tiles
#define NB_H0   4
#define NB_ALL  (NB_SCAN + NB_GI + NB_H0 + 1)   // 825

typedef __bf16 bf16x8_t __attribute__((ext_vector_type(8)));
typedef float  f32x4_t  __attribute__((ext_vector_type(4)));
typedef short  s16x8_t  __attribute__((ext_vector_type(8)));
typedef unsigned long long ull_t;

typedef __attribute__((address_space(3))) char*       lds_cptr_t;
typedef const __attribute__((address_space(1))) char* glb_cptr_t;

__device__ __forceinline__ void gload_lds16(const void* g, void* l) {
  __builtin_amdgcn_global_load_lds((glb_cptr_t)g, (lds_cptr_t)l, 16, 0, 0);
}
__device__ __forceinline__ float bf2f(short s) {
  return __uint_as_float(((unsigned)(unsigned short)s) << 16);
}
__device__ __forceinline__ short f2bf(float f) {
  __hip_bfloat16 h = __float2bfloat16(f);  // RNE
  return *reinterpret_cast<short*>(&h);
}
__device__ __forceinline__ s16x8_t cvt8(const float* p) {
  f32x4_t lo = *reinterpret_cast<const f32x4_t*>(p);
  f32x4_t hi = *reinterpret_cast<const f32x4_t*>(p + 4);
  s16x8_t r;
#pragma unroll
  for (int e = 0; e < 4; e++) { r[e] = f2bf(lo[e]); r[4 + e] = f2bf(hi[e]); }
  return r;
}
__device__ __forceinline__ float sigmoidf_(float x) {
  return 1.0f / (1.0f + __expf(-x));
}
__device__ __forceinline__ bf16x8_t lds_frag(const short* p) {
  return __builtin_bit_cast(bf16x8_t, *reinterpret_cast<const s16x8_t*>(p));
}
__device__ __forceinline__ void store_short_llc(ull_t addr, unsigned val) {
  asm volatile("global_store_short %0, %1, off sc0 sc1"
               :: "v"(addr), "v"(val) : "memory");
}
__device__ __forceinline__ unsigned load_ushort_llc(const void* p) {
  unsigned v;
  asm volatile("global_load_ushort %0, %1, off sc0 sc1" : "=v"(v) : "v"(p));
  return v;
}

// ---------------- fused f32 -> bf16 converts (6 segments, 1 launch) ----------------
__global__ void GG_cvt6(const float* __restrict__ whh, __hip_bfloat16* __restrict__ dwhh,
                        const float* __restrict__ wih, __hip_bfloat16* __restrict__ dwih,
                        const float* __restrict__ wemb, __hip_bfloat16* __restrict__ dwemb,
                        const float* __restrict__ winit, __hip_bfloat16* __restrict__ dwinit,
                        const float* __restrict__ gf, __hip_bfloat16* __restrict__ dgf,
                        const float* __restrict__ wfc, __hip_bfloat16* __restrict__ dwfc) {
  const int i = blockIdx.x * blockDim.x + threadIdx.x;
  const float* s; __hip_bfloat16* d; int off;
  if (i < 98304)        { s = whh;   d = dwhh;   off = i; }
  else if (i < 196608)  { s = wih;   d = dwih;   off = i - 98304; }
  else if (i < 836608)  { s = wemb;  d = dwemb;  off = i - 196608; }
  else if (i < 967680)  { s = winit; d = dwinit; off = i - 836608; }
  else if (i < 1000448) { s = gf;    d = dgf;    off = i - 967680; }
  else {
    if (dwfc == nullptr || i >= 1640448) return;
    s = wfc; d = dwfc; off = i - 1000448;
  }
  s16x8_t v = cvt8(s + (long)off * 8);
  *reinterpret_cast<s16x8_t*>(d + (long)off * 8) = v;
}

// ---------------- logits GEMM v3: 128x256 tile, 8 waves, T2-swizzled ----------------
template <bool BBF16>
__global__ __launch_bounds__(512) void GG_gemm_logits(
    const __hip_bfloat16* __restrict__ hfull,  // [B][64][512]
    const void* __restrict__ Bsrc,             // W_fc bf16 or f32 [V][512]
    const float* __restrict__ bias,            // [V] f32
    float* __restrict__ C) {                   // [M][V]  (m = b*63+t)
  const int flat = blockIdx.x;
  const int xcd = flat & 7;
  const int s = flat >> 3;            // 0..314
  const int col = xcd * 5 + s % 5;    // 0..39
  const int row = s / 5;              // 0..62
  const int m0 = row * 128;
  const int n0 = col * 256;

  __shared__ short sA[128 * 64];  // 16 KB
  __shared__ short sB[256 * 64];  // 32 KB
  const int lane = threadIdx.x & 63;
  const int wave = threadIdx.x >> 6;  // 0..7
  const int srow = lane >> 3;
  const int scol  = (lane & 7) * 8;
  const int scolz = ((lane & 7) ^ (srow & 7)) * 8;

  f32x4_t acc[4][4] = {};

  const __hip_bfloat16* aptr[2];
#pragma unroll
  for (int i = 0; i < 2; i++) {
    const int r = (wave + i * 8) * 8 + srow;
    const int m = m0 + r;
    const int bb = m / 63;
    const int tt = m - bb * 63;
    aptr[i] = hfull + ((long)bb * 64 + tt + 1) * 512 + scolz;
  }
  const __hip_bfloat16* bptrB[4];
  const float* bptrF[4];
#pragma unroll
  for (int i = 0; i < 4; i++) {
    int nrow = n0 + (wave + i * 8) * 8 + srow;
    nrow = (nrow < V_) ? nrow : (V_ - 1);
    if constexpr (BBF16) bptrB[i] = (const __hip_bfloat16*)Bsrc + (long)nrow * 512 + scolz;
    else                 bptrF[i] = (const float*)Bsrc + (long)nrow * 512 + scol;
  }

  const int wm = (wave >> 2) * 64;
  const int wn = (wave & 3) * 64;
  const int fr = lane & 15;
  const int g4 = lane >> 4;

  for (int kt = 0; kt < 8; kt++) {
    s16x8_t vb[4];
    if constexpr (!BBF16) {
#pragma unroll
      for (int i = 0; i < 4; i++) vb[i] = cvt8(bptrF[i] + kt * 64);
    }
    __syncthreads();
#pragma unroll
    for (int i = 0; i < 2; i++)
      gload_lds16(aptr[i] + kt * 64, sA + (wave + i * 8) * 512);
#pragma unroll
    for (int i = 0; i < 4; i++) {
      if constexpr (BBF16)
        gload_lds16(bptrB[i] + kt * 64, sB + (wave + i * 8) * 512);
      else
        *reinterpret_cast<s16x8_t*>(
            sB + (wave + i * 8) * 512 + srow * 64 + (((lane & 7) ^ (srow & 7)) * 8)) = vb[i];
    }
    __syncthreads();
#pragma unroll
    for (int kk = 0; kk < 2; kk++) {
      const int gsw = ((kk * 4 + g4) ^ (fr & 7)) * 8;
      bf16x8_t a[4], b[4];
#pragma unroll
      for (int i = 0; i < 4; i++) {
        a[i] = lds_frag(sA + (wm + i * 16 + fr) * 64 + gsw);
        b[i] = lds_frag(sB + (wn + i * 16 + fr) * 64 + gsw);
      }
#pragma unroll
      for (int i = 0; i < 4; i++)
#pragma unroll
        for (int j = 0; j < 4; j++)
          acc[i][j] = __builtin_amdgcn_mfma_f32_16x16x32_bf16(a[i], b[j], acc[i][j], 0, 0, 0);
    }
  }

  const int fq = lane >> 4;
#pragma unroll
  for (int j = 0; j < 4; j++) {
    const int n = n0 + wn + j * 16 + fr;
    if (n >= V_) continue;
    const float bv = bias[n];
#pragma unroll
    for (int i = 0; i < 4; i++)
#pragma unroll
      for (int rr = 0; rr < 4; rr++) {
        const int m = m0 + wm + i * 16 + fq * 4 + rr;
        C[(long)m * V_ + n] = acc[i][j][rr] + bv;
      }
  }
}

// ---------------- MEGA kernel: scan (0..63) + gi (64..819) + h0 (820..823) + tail ----
// gi is t-major: gi[t][b][gate], so scan step t needs only gicnt[t] == 12.
// All cross-block data moves via LLC (sc0 sc1) + relaxed SYSTEM atomics.
// flags layout (ints): [0..63] h-flags (2 groups of 32), [64..126] gicnt[t],
// [127] h0cnt.
__global__ __launch_bounds__(256) void GG_mega(
    __hip_bfloat16* __restrict__ hfull,       // [B][64][512]
    __hip_bfloat16* __restrict__ gi,          // [T][B][G] t-major
    const __hip_bfloat16* __restrict__ WhhB,  // [G][512]
    const float* __restrict__ bhh,            // [G]
    int* __restrict__ flags,
    const __hip_bfloat16* __restrict__ gfB,     // [128][2048]
    const __hip_bfloat16* __restrict__ WinitB,  // [512][2048]
    const float* __restrict__ binit,            // [512]
    const __hip_bfloat16* __restrict__ WembB,   // [V][512]
    const int* __restrict__ cap,                // [B][L]
    const __hip_bfloat16* __restrict__ WihB,    // [G][512]
    const float* __restrict__ bih,              // [G]
    const int* __restrict__ lens,
    float* __restrict__ out) {
  __shared__ short smem[48 * 512];  // scan: sW 48KB | gemm roles: sA 16K + sB 16K
  const int lane = threadIdx.x & 63;
  const int wave = threadIdx.x >> 6;
  const int fr = lane & 15;
  const int g4 = lane >> 4;
  int* gicnt = flags + 64;
  int* h0cnt = flags + 127;

  if (blockIdx.x < NB_SCAN) {
    // ================= scan role (R17 inner loop; t-major gi) =================
    short* sW = smem;
    const int strip = blockIdx.x & 31;
    const int half  = blockIdx.x >> 5;
    const int d0 = strip * 16;
    int* myflags = flags + half * 32;

    for (int rr = wave; rr < 48; rr += 4) {
      const int grow = (rr >> 4) * 512 + d0 + (rr & 15);
      gload_lds16(WhhB + (long)grow * 512 + (lane ^ (rr & 7)) * 8, sW + rr * 512);
    }

    const int dd = d0 + fr;
    const int bbase = half * 64 + wave * 16 + g4 * 4;
    const float br_ = bhh[dd], bz_ = bhh[512 + dd], bn_ = bhh[1024 + dd];
    const short* gis = (const short*)gi;

    const int arow = half * 64 + wave * 16 + fr;
    const ull_t abase0 =
        (ull_t)hfull + ((ull_t)arow * 64 * 512 + (unsigned)(g4 * 8)) * 2ull;

    ull_t sbase[4];
    const short* gp0[4];  // t-major: row base for t=0
#pragma unroll
    for (int rr = 0; rr < 4; rr++) {
      sbase[rr] = (ull_t)hfull +
                  ((ull_t)(bbase + rr) * 64 * 512 + (unsigned)dd) * 2ull;
      gp0[rr] = gis + (long)(bbase + rr) * G_ + dd;
    }

    // wait h0 done, then load hp via LLC
    while (__hip_atomic_load(h0cnt, __ATOMIC_RELAXED, __HIP_MEMORY_SCOPE_SYSTEM) < NB_H0)
      __builtin_amdgcn_s_sleep(8);
    float hp[4];
    unsigned hpu[4];
#pragma unroll
    for (int rr = 0; rr < 4; rr++)
      hpu[rr] = load_ushort_llc((const char*)hfull +
                                ((long)(bbase + rr) * 64 * 512 + dd) * 2);
    // wait gi(t=0) ready, then load gi(0) via LLC
    while (__hip_atomic_load(&gicnt[0], __ATOMIC_RELAXED, __HIP_MEMORY_SCOPE_SYSTEM) < 12)
      __builtin_amdgcn_s_sleep(8);
    unsigned cr[4], cz[4], cn[4];
#pragma unroll
    for (int rr = 0; rr < 4; rr++) {
      const short* gp = gp0[rr];
      cr[rr] = load_ushort_llc(gp);
      cz[rr] = load_ushort_llc(gp + 512);
      cn[rr] = load_ushort_llc(gp + 1024);
    }
    asm volatile("s_waitcnt vmcnt(0)" ::: "memory");
#pragma unroll
    for (int rr = 0; rr < 4; rr++) hp[rr] = bf2f((short)hpu[rr]);
    __syncthreads();  // sW fully staged

    for (int t = 0; t < T_; t++) {
      // ---- clean poll: h-flags(t) AND gicnt[t+1] ----
      {
        const bool needg = (t < T_ - 1);
        while (true) {
          int hok = 1;
          if (t > 0) {
            const int v = __hip_atomic_load(&myflags[lane & 31], __ATOMIC_RELAXED,
                                            __HIP_MEMORY_SCOPE_SYSTEM);
            hok = __all(v >= t) ? 1 : 0;
          }
          int gok = 1;
          if (needg)
            gok = (__hip_atomic_load(&gicnt[t + 1], __ATOMIC_RELAXED,
                                     __HIP_MEMORY_SCOPE_SYSTEM) >= 12) ? 1 : 0;
          if (hok && gok) break;
          __builtin_amdgcn_s_sleep(1);
        }
      }

      // ---- 16 A-loads, LLC-coherent ----
      const ull_t ab = abase0 + (ull_t)t * 1024ull;
      f32x4_t a[16];
#define ALOAD(IDX, OFF)                                                        \
      asm volatile("global_load_dwordx4 %0, %1, off offset:" #OFF " sc0 sc1"   \
                   : "=v"(a[IDX]) : "v"(ab));
      ALOAD(0, 0)    ALOAD(1, 64)   ALOAD(2, 128)  ALOAD(3, 192)
      ALOAD(4, 256)  ALOAD(5, 320)  ALOAD(6, 384)  ALOAD(7, 448)
      ALOAD(8, 512)  ALOAD(9, 576)  ALOAD(10, 640) ALOAD(11, 704)
      ALOAD(12, 768) ALOAD(13, 832) ALOAD(14, 896) ALOAD(15, 960)
#undef ALOAD

      // ---- gi(t+1) prefetch (LLC loads, issued AFTER A; FIFO) ----
      const int tp = (t < T_ - 1) ? (t + 1) : (T_ - 1);
      unsigned nr[4], nz[4], nn[4];
#pragma unroll
      for (int rr = 0; rr < 4; rr++) {
        const short* gp = gp0[rr] + (long)tp * (B_ * G_);
        nr[rr] = load_ushort_llc(gp);
        nz[rr] = load_ushort_llc(gp + 512);
        nn[rr] = load_ushort_llc(gp + 1024);
      }

      asm volatile("s_waitcnt vmcnt(12)" ::: "memory");  // A ready; gi in flight
      __builtin_amdgcn_sched_barrier(0);

      f32x4_t acc[3] = {};
#pragma unroll
      for (int kt = 0; kt < 16; kt++) {
        const bf16x8_t afr = __builtin_bit_cast(bf16x8_t, a[kt]);
        const int gsw = ((kt * 4 + g4) ^ (fr & 7)) * 8;
        bf16x8_t bfr[3];
#pragma unroll
        for (int j = 0; j < 3; j++) bfr[j] = lds_frag(sW + (j * 16 + fr) * 512 + gsw);
#pragma unroll
        for (int j = 0; j < 3; j++)
          acc[j] = __builtin_amdgcn_mfma_f32_16x16x32_bf16(afr, bfr[j], acc[j], 0, 0, 0);
      }

#pragma unroll
      for (int rr = 0; rr < 4; rr++) {
        const float rg = sigmoidf_(bf2f((short)cr[rr]) + acc[0][rr] + br_);
        const float zg = sigmoidf_(bf2f((short)cz[rr]) + acc[1][rr] + bz_);
        const float ng = tanhf(bf2f((short)cn[rr]) + rg * (acc[2][rr] + bn_));
        const short hnb = f2bf((1.f - zg) * ng + zg * hp[rr]);
        hp[rr] = bf2f(hnb);
        store_short_llc(sbase[rr] + (ull_t)(t + 1) * 1024ull, (unsigned short)hnb);
      }

      asm volatile("s_waitcnt vmcnt(0)" ::: "memory");  // stores acked; gi drained
      __builtin_amdgcn_sched_barrier(0);
#pragma unroll
      for (int rr = 0; rr < 4; rr++) { cr[rr] = nr[rr]; cz[rr] = nz[rr]; cn[rr] = nn[rr]; }

      if (t < T_ - 1) {
        __syncthreads();  // whole block's stores drained
        if (threadIdx.x == 0)
          __hip_atomic_store(&myflags[strip], t + 1, __ATOMIC_RELAXED,
                             __HIP_MEMORY_SCOPE_SYSTEM);
      }
    }
    return;
  }

  if (blockIdx.x >= NB_SCAN + NB_GI + NB_H0) {  // ---- tail ----
    if (threadIdx.x < B_) out[LOGITS_SZ + threadIdx.x] = (float)(lens[threadIdx.x] - 1);
    return;
  }

  // ---- GEMM roles (gi / h0) share structure ----
  short* sA = smem;
  short* sB = smem + 128 * 64;
  const int srow = lane >> 3;
  const int scolz = ((lane & 7) ^ (srow & 7)) * 8;
  const int wm = (wave >> 1) * 64;
  const int wn = (wave & 1) * 64;
  f32x4_t acc[4][4] = {};
  const int fq = lane >> 4;

  if (blockIdx.x >= NB_SCAN + NB_GI) {
    // ---- h0: M=128, N=128(of 512), K=2048; sc0sc1 stores + h0cnt ----
    const int n0 = (blockIdx.x - NB_SCAN - NB_GI) * 128;
    const __hip_bfloat16* aptr[4];
    const __hip_bfloat16* bptr[4];
#pragma unroll
    for (int i = 0; i < 4; i++) {
      const int r = (wave * 4 + i) * 8 + srow;
      aptr[i] = gfB + (long)r * ENC_ + scolz;
      bptr[i] = WinitB + (long)(n0 + r) * ENC_ + scolz;
    }
    for (int kt = 0; kt < 32; kt++) {
      __syncthreads();
#pragma unroll
      for (int i = 0; i < 4; i++) {
        const int chunk = wave * 4 + i;
        gload_lds16(aptr[i] + kt * 64, sA + chunk * 512);
        gload_lds16(bptr[i] + kt * 64, sB + chunk * 512);
      }
      __syncthreads();
#pragma unroll
      for (int kk = 0; kk < 2; kk++) {
        const int gsw = ((kk * 4 + g4) ^ (fr & 7)) * 8;
        bf16x8_t a[4], b[4];
#pragma unroll
        for (int i = 0; i < 4; i++) {
          a[i] = lds_frag(sA + (wm + i * 16 + fr) * 64 + gsw);
          b[i] = lds_frag(sB + (wn + i * 16 + fr) * 64 + gsw);
        }
#pragma unroll
        for (int i = 0; i < 4; i++)
#pragma unroll
          for (int j = 0; j < 4; j++)
            acc[i][j] = __builtin_amdgcn_mfma_f32_16x16x32_bf16(a[i], b[j], acc[i][j], 0, 0, 0);
      }
    }
#pragma unroll
    for (int j = 0; j < 4; j++) {
      const int n = n0 + wn + j * 16 + fr;
      const float bv = binit[n];
#pragma unroll
      for (int i = 0; i < 4; i++)
#pragma unroll
        for (int rr = 0; rr < 4; rr++) {
          const int m = wm + i * 16 + fq * 4 + rr;
          const short hv = f2bf(tanhf(acc[i][j][rr] + bv));
          store_short_llc((ull_t)hfull + ((ull_t)m * 64 * 512 + n) * 2ull,
                          (unsigned short)hv);
        }
    }
    asm volatile("s_waitcnt vmcnt(0)" ::: "memory");
    __syncthreads();
    if (threadIdx.x == 0)
      __hip_atomic_fetch_add(h0cnt, 1, __ATOMIC_RELAXED, __HIP_MEMORY_SCOPE_SYSTEM);
    return;
  }

  // ---- gi tile: t-major; flat = (t, nb); sc0sc1 stores + gicnt[t] ----
  const int flat = blockIdx.x - NB_SCAN;
  const int tt = flat / 12;           // 0..62
  const int n0 = (flat % 12) * 128;
  const __hip_bfloat16* aptr[4];
  const __hip_bfloat16* bptr[4];
#pragma unroll
  for (int i = 0; i < 4; i++) {
    const int b = (wave * 4 + i) * 8 + srow;   // row in tile == batch
    aptr[i] = WembB + (long)cap[b * L_ + tt] * 512 + scolz;
    bptr[i] = WihB + (long)(n0 + (wave * 4 + i) * 8 + srow) * 512 + scolz;
  }
  for (int kt = 0; kt < 8; kt++) {
    __syncthreads();
#pragma unroll
    for (int i = 0; i < 4; i++) {
      const int chunk = wave * 4 + i;
      gload_lds16(aptr[i] + kt * 64, sA + chunk * 512);
      gload_lds16(bptr[i] + kt * 64, sB + chunk * 512);
    }
    __syncthreads();
#pragma unroll
    for (int kk = 0; kk < 2; kk++) {
      const int gsw = ((kk * 4 + g4) ^ (fr & 7)) * 8;
      bf16x8_t a[4], b[4];
#pragma unroll
      for (int i = 0; i < 4; i++) {
        a[i] = lds_frag(sA + (wm + i * 16 + fr) * 64 + gsw);
        b[i] = lds_frag(sB + (wn + i * 16 + fr) * 64 + gsw);
      }
#pragma unroll
      for (int i = 0; i < 4; i++)
#pragma unroll
        for (int j = 0; j < 4; j++)
          acc[i][j] = __builtin_amdgcn_mfma_f32_16x16x32_bf16(a[i], b[j], acc[i][j], 0, 0, 0);
    }
  }
#pragma unroll
  for (int j = 0; j < 4; j++) {
    const int n = n0 + wn + j * 16 + fr;
    const float bv = bih[n];
#pragma unroll
    for (int i = 0; i < 4; i++)
#pragma unroll
      for (int rr = 0; rr < 4; rr++) {
        const int b = wm + i * 16 + fq * 4 + rr;
        const short gv = f2bf(acc[i][j][rr] + bv);
        store_short_llc((ull_t)gi + (((ull_t)tt * B_ + b) * G_ + n) * 2ull,
                        (unsigned short)gv);
      }
  }
  asm volatile("s_waitcnt vmcnt(0)" ::: "memory");
  __syncthreads();
  if (threadIdx.x == 0)
    __hip_atomic_fetch_add(&gicnt[tt], 1, __ATOMIC_RELAXED, __HIP_MEMORY_SCOPE_SYSTEM);
}

extern "C" void kernel_launch(void* const* d_in, const int* in_sizes, int n_in,
                              void* d_out, int out_size, void* d_ws, size_t ws_size,
                              hipStream_t stream) {
  const float* gf      = (const float*)d_in[0];
  const int*   cap     = (const int*)d_in[1];
  const int*   lens    = (const int*)d_in[2];
  const float* W_embed = (const float*)d_in[3];
  const float* W_init  = (const float*)d_in[4];
  const float* b_init  = (const float*)d_in[5];
  const float* W_ih    = (const float*)d_in[6];
  const float* W_hh    = (const float*)d_in[7];
  const float* b_ih    = (const float*)d_in[8];
  const float* b_hh    = (const float*)d_in[9];
  const float* W_fc    = (const float*)d_in[10];
  const float* b_fc    = (const float*)d_in[11];
  float* out = (float*)d_out;

  // d_out scratch (all consumed before the logits GEMM writes d_out):
  char* ob = (char*)d_out;
  __hip_bfloat16* gi_ws  = (__hip_bfloat16*)ob;               // [0, 24,772,608) t-major
  __hip_bfloat16* WhhB   = (__hip_bfloat16*)(ob + 25165824);  // 1.5 MB
  __hip_bfloat16* WihB   = (__hip_bfloat16*)(ob + 27262976);  // 1.5 MB
  __hip_bfloat16* WembB  = (__hip_bfloat16*)(ob + 29360128);  // 10 MB
  __hip_bfloat16* WinitB = (__hip_bfloat16*)(ob + 40894464);  // 2 MB
  __hip_bfloat16* gfB    = (__hip_bfloat16*)(ob + 43253760);  // 0.5 MB

  // ws: hfull [B][64][512] bf16 + WfcB + flags
  __hip_bfloat16* hfull = (__hip_bfloat16*)d_ws;
  __hip_bfloat16* WfcB  = (__hip_bfloat16*)((char*)d_ws + 8388608);
  const bool big_ws = ws_size >= (size_t)(8388608 + 10240000 + 512);
  int* flags = (int*)((char*)d_ws + (big_ws ? 18628608 : 8388608));

  // 0. reset flags (h-flags + gicnt + h0cnt)
  hipMemsetAsync(flags, 0, 512, stream);

  // 1. all weight/input converts in ONE launch
  GG_cvt6<<<dim3(6408), 256, 0, stream>>>(W_hh, WhhB, W_ih, WihB, W_embed, WembB,
                                          W_init, WinitB, gf, gfB,
                                          W_fc, big_ws ? WfcB : nullptr);

  // 2. MEGA: scan + gi + h0 + tail, flag-coordinated, all co-resident
  GG_mega<<<dim3(NB_ALL), 256, 0, stream>>>(hfull, gi_ws, WhhB, b_hh, flags,
                                            gfB, WinitB, b_init,
                                            WembB, cap, WihB, b_ih, lens, out);

  // 3. logits: 128x256 tile, 8 waves, XCD-banded, T2-swizzled
  if (big_ws)
    GG_gemm_logits<true><<<dim3(2520), 512, 0, stream>>>(hfull, WfcB, b_fc, out);
  else
    GG_gemm_logits<false><<<dim3(2520), 512, 0, stream>>>(hfull, W_fc, b_fc, out);
}

// Round 19
// 492.196 us; speedup vs baseline: 1.1000x; 1.1000x over previous
//
#include <hip/hip_runtime.h>
#include <hip/hip_bf16.h>

// Problem dims
#define V_    10000
#define ENC_  2048
#define D_    512
#define B_    128
#define L_    64
#define T_    63          // L-1 timesteps
#define M_    (B_ * L_ - B_)   // 8064 rows (b*63 + t)
#define G_    (3 * D_)    // 1536 gate width
#define LOGITS_SZ ((long)M_ * V_)   // 80,640,000
#define SCAN_NB 64        // 2 batch-halves x 32 d-strips (16-wide)

typedef __bf16 bf16x8_t __attribute__((ext_vector_type(8)));
typedef float  f32x4_t  __attribute__((ext_vector_type(4)));
typedef short  s16x8_t  __attribute__((ext_vector_type(8)));
typedef unsigned long long ull_t;

typedef __attribute__((address_space(3))) char*       lds_cptr_t;
typedef const __attribute__((address_space(1))) char* glb_cptr_t;

__device__ __forceinline__ void gload_lds16(const void* g, void* l) {
  __builtin_amdgcn_global_load_lds((glb_cptr_t)g, (lds_cptr_t)l, 16, 0, 0);
}
__device__ __forceinline__ float bf2f(short s) {
  return __uint_as_float(((unsigned)(unsigned short)s) << 16);
}
__device__ __forceinline__ short f2bf(float f) {
  __hip_bfloat16 h = __float2bfloat16(f);  // RNE
  return *reinterpret_cast<short*>(&h);
}
__device__ __forceinline__ s16x8_t cvt8(const float* p) {
  f32x4_t lo = *reinterpret_cast<const f32x4_t*>(p);
  f32x4_t hi = *reinterpret_cast<const f32x4_t*>(p + 4);
  s16x8_t r;
#pragma unroll
  for (int e = 0; e < 4; e++) { r[e] = f2bf(lo[e]); r[4 + e] = f2bf(hi[e]); }
  return r;
}
__device__ __forceinline__ float sigmoidf_(float x) {
  return 1.0f / (1.0f + __expf(-x));
}
__device__ __forceinline__ bf16x8_t lds_frag(const short* p) {
  return __builtin_bit_cast(bf16x8_t, *reinterpret_cast<const s16x8_t*>(p));
}

// ---------------- fused f32 -> bf16 converts (6 segments, 1 launch) ----------------
__global__ void GG_cvt6(const float* __restrict__ whh, __hip_bfloat16* __restrict__ dwhh,
                        const float* __restrict__ wih, __hip_bfloat16* __restrict__ dwih,
                        const float* __restrict__ wemb, __hip_bfloat16* __restrict__ dwemb,
                        const float* __restrict__ winit, __hip_bfloat16* __restrict__ dwinit,
                        const float* __restrict__ gf, __hip_bfloat16* __restrict__ dgf,
                        const float* __restrict__ wfc, __hip_bfloat16* __restrict__ dwfc) {
  const int i = blockIdx.x * blockDim.x + threadIdx.x;
  const float* s; __hip_bfloat16* d; int off;
  if (i < 98304)        { s = whh;   d = dwhh;   off = i; }
  else if (i < 196608)  { s = wih;   d = dwih;   off = i - 98304; }
  else if (i < 836608)  { s = wemb;  d = dwemb;  off = i - 196608; }
  else if (i < 967680)  { s = winit; d = dwinit; off = i - 836608; }
  else if (i < 1000448) { s = gf;    d = dgf;    off = i - 967680; }
  else {
    if (dwfc == nullptr || i >= 1640448) return;
    s = wfc; d = dwfc; off = i - 1000448;
  }
  s16x8_t v = cvt8(s + (long)off * 8);
  *reinterpret_cast<s16x8_t*>(d + (long)off * 8) = v;
}

// ---------------- fused prep: h0 GEMM (blk 0..3) + gi GEMM (blk 4..759) + tail (760) ----
__global__ __launch_bounds__(256) void GG_prep(
    const __hip_bfloat16* __restrict__ gfB,     // [128][2048]
    const __hip_bfloat16* __restrict__ WinitB,  // [512][2048]
    const float* __restrict__ binit,            // [512]
    __hip_bfloat16* __restrict__ hfull,         // [B][64][512]
    const __hip_bfloat16* __restrict__ WembB,   // [V][512]
    const int* __restrict__ cap,                // [B][L]
    const __hip_bfloat16* __restrict__ WihB,    // [G][512]
    const float* __restrict__ bih,              // [G]
    __hip_bfloat16* __restrict__ giC,           // [M][G]
    const int* __restrict__ lens,
    float* __restrict__ out) {
  __shared__ short smem[2 * 128 * 64];
  short* sA = smem;
  short* sB = smem + 128 * 64;
  const int lane = threadIdx.x & 63;
  const int wave = threadIdx.x >> 6;
  const int srow = lane >> 3;
  const int scolz = ((lane & 7) ^ (srow & 7)) * 8;  // T2 pre-swizzled source granule
  const int fr = lane & 15;
  const int g4 = lane >> 4;
  const int wm = (wave >> 1) * 64;
  const int wn = (wave & 1) * 64;

  if (blockIdx.x >= 760) {  // ---- tail ----
    if (threadIdx.x < B_) out[LOGITS_SZ + threadIdx.x] = (float)(lens[threadIdx.x] - 1);
    return;
  }

  f32x4_t acc[4][4] = {};

  if (blockIdx.x < 4) {  // ---- h0: M=128, N=128(of 512), K=2048 ----
    const int n0 = blockIdx.x * 128;
    const __hip_bfloat16* aptr[4];
    const __hip_bfloat16* bptr[4];
#pragma unroll
    for (int i = 0; i < 4; i++) {
      const int r = (wave * 4 + i) * 8 + srow;
      aptr[i] = gfB + (long)r * ENC_ + scolz;
      bptr[i] = WinitB + (long)(n0 + r) * ENC_ + scolz;
    }
    for (int kt = 0; kt < 32; kt++) {
      __syncthreads();
#pragma unroll
      for (int i = 0; i < 4; i++) {
        const int chunk = wave * 4 + i;
        gload_lds16(aptr[i] + kt * 64, sA + chunk * 512);
        gload_lds16(bptr[i] + kt * 64, sB + chunk * 512);
      }
      __syncthreads();
#pragma unroll
      for (int kk = 0; kk < 2; kk++) {
        const int gsw = ((kk * 4 + g4) ^ (fr & 7)) * 8;
        bf16x8_t a[4], b[4];
#pragma unroll
        for (int i = 0; i < 4; i++) {
          a[i] = lds_frag(sA + (wm + i * 16 + fr) * 64 + gsw);
          b[i] = lds_frag(sB + (wn + i * 16 + fr) * 64 + gsw);
        }
#pragma unroll
        for (int i = 0; i < 4; i++)
#pragma unroll
          for (int j = 0; j < 4; j++)
            acc[i][j] = __builtin_amdgcn_mfma_f32_16x16x32_bf16(a[i], b[j], acc[i][j], 0, 0, 0);
      }
    }
    const int fq = lane >> 4;
#pragma unroll
    for (int j = 0; j < 4; j++) {
      const int n = n0 + wn + j * 16 + fr;
      const float bv = binit[n];
#pragma unroll
      for (int i = 0; i < 4; i++)
#pragma unroll
        for (int rr = 0; rr < 4; rr++) {
          const int m = wm + i * 16 + fq * 4 + rr;
          hfull[(long)m * 64 * 512 + n] = __float2bfloat16(tanhf(acc[i][j][rr] + bv));
        }
    }
    return;
  }

  // ---- gi: M=8064, N=1536, K=512; flat tile index ----
  const int flat = blockIdx.x - 4;
  const int m0 = (flat / 12) * 128;
  const int n0 = (flat % 12) * 128;
  const __hip_bfloat16* aptr[4];
  const __hip_bfloat16* bptr[4];
#pragma unroll
  for (int i = 0; i < 4; i++) {
    const int r = (wave * 4 + i) * 8 + srow;
    const int bt = m0 + r;
    const int bb = bt / 63;
    const int tt = bt - bb * 63;
    aptr[i] = WembB + (long)cap[bb * L_ + tt] * 512 + scolz;
    bptr[i] = WihB + (long)(n0 + r) * 512 + scolz;
  }
  for (int kt = 0; kt < 8; kt++) {
    __syncthreads();
#pragma unroll
    for (int i = 0; i < 4; i++) {
      const int chunk = wave * 4 + i;
      gload_lds16(aptr[i] + kt * 64, sA + chunk * 512);
      gload_lds16(bptr[i] + kt * 64, sB + chunk * 512);
    }
    __syncthreads();
#pragma unroll
    for (int kk = 0; kk < 2; kk++) {
      const int gsw = ((kk * 4 + g4) ^ (fr & 7)) * 8;
      bf16x8_t a[4], b[4];
#pragma unroll
      for (int i = 0; i < 4; i++) {
        a[i] = lds_frag(sA + (wm + i * 16 + fr) * 64 + gsw);
        b[i] = lds_frag(sB + (wn + i * 16 + fr) * 64 + gsw);
      }
#pragma unroll
      for (int i = 0; i < 4; i++)
#pragma unroll
        for (int j = 0; j < 4; j++)
          acc[i][j] = __builtin_amdgcn_mfma_f32_16x16x32_bf16(a[i], b[j], acc[i][j], 0, 0, 0);
    }
  }
  const int fq = lane >> 4;
#pragma unroll
  for (int j = 0; j < 4; j++) {
    const int n = n0 + wn + j * 16 + fr;
    const float bv = bih[n];
#pragma unroll
    for (int i = 0; i < 4; i++)
#pragma unroll
      for (int rr = 0; rr < 4; rr++) {
        const int m = m0 + wm + i * 16 + fq * 4 + rr;
        giC[(long)m * G_ + n] = __float2bfloat16(acc[i][j][rr] + bv);
      }
  }
}

// ---------------- logits GEMM v3: 128x256 tile, 8 waves, T2-swizzled ----------------
template <bool BBF16>
__global__ __launch_bounds__(512) void GG_gemm_logits(
    const __hip_bfloat16* __restrict__ hfull,  // [B][64][512]
    const void* __restrict__ Bsrc,             // W_fc bf16 or f32 [V][512]
    const float* __restrict__ bias,            // [V] f32
    float* __restrict__ C) {                   // [M][V]
  const int flat = blockIdx.x;
  const int xcd = flat & 7;
  const int s = flat >> 3;            // 0..314
  const int col = xcd * 5 + s % 5;    // 0..39
  const int row = s / 5;              // 0..62
  const int m0 = row * 128;
  const int n0 = col * 256;

  __shared__ short sA[128 * 64];  // 16 KB
  __shared__ short sB[256 * 64];  // 32 KB
  const int lane = threadIdx.x & 63;
  const int wave = threadIdx.x >> 6;  // 0..7
  const int srow = lane >> 3;
  const int scol  = (lane & 7) * 8;
  const int scolz = ((lane & 7) ^ (srow & 7)) * 8;

  f32x4_t acc[4][4] = {};

  const __hip_bfloat16* aptr[2];
#pragma unroll
  for (int i = 0; i < 2; i++) {
    const int r = (wave + i * 8) * 8 + srow;
    const int m = m0 + r;
    const int bb = m / 63;
    const int tt = m - bb * 63;
    aptr[i] = hfull + ((long)bb * 64 + tt + 1) * 512 + scolz;
  }
  const __hip_bfloat16* bptrB[4];
  const float* bptrF[4];
#pragma unroll
  for (int i = 0; i < 4; i++) {
    int nrow = n0 + (wave + i * 8) * 8 + srow;
    nrow = (nrow < V_) ? nrow : (V_ - 1);
    if constexpr (BBF16) bptrB[i] = (const __hip_bfloat16*)Bsrc + (long)nrow * 512 + scolz;
    else                 bptrF[i] = (const float*)Bsrc + (long)nrow * 512 + scol;
  }

  const int wm = (wave >> 2) * 64;
  const int wn = (wave & 3) * 64;
  const int fr = lane & 15;
  const int g4 = lane >> 4;

  for (int kt = 0; kt < 8; kt++) {
    s16x8_t vb[4];
    if constexpr (!BBF16) {
#pragma unroll
      for (int i = 0; i < 4; i++) vb[i] = cvt8(bptrF[i] + kt * 64);
    }
    __syncthreads();
#pragma unroll
    for (int i = 0; i < 2; i++)
      gload_lds16(aptr[i] + kt * 64, sA + (wave + i * 8) * 512);
#pragma unroll
    for (int i = 0; i < 4; i++) {
      if constexpr (BBF16)
        gload_lds16(bptrB[i] + kt * 64, sB + (wave + i * 8) * 512);
      else
        *reinterpret_cast<s16x8_t*>(
            sB + (wave + i * 8) * 512 + srow * 64 + (((lane & 7) ^ (srow & 7)) * 8)) = vb[i];
    }
    __syncthreads();
#pragma unroll
    for (int kk = 0; kk < 2; kk++) {
      const int gsw = ((kk * 4 + g4) ^ (fr & 7)) * 8;
      bf16x8_t a[4], b[4];
#pragma unroll
      for (int i = 0; i < 4; i++) {
        a[i] = lds_frag(sA + (wm + i * 16 + fr) * 64 + gsw);
        b[i] = lds_frag(sB + (wn + i * 16 + fr) * 64 + gsw);
      }
#pragma unroll
      for (int i = 0; i < 4; i++)
#pragma unroll
        for (int j = 0; j < 4; j++)
          acc[i][j] = __builtin_amdgcn_mfma_f32_16x16x32_bf16(a[i], b[j], acc[i][j], 0, 0, 0);
    }
  }

  const int fq = lane >> 4;
#pragma unroll
  for (int j = 0; j < 4; j++) {
    const int n = n0 + wn + j * 16 + fr;
    if (n >= V_) continue;
    const float bv = bias[n];
#pragma unroll
    for (int i = 0; i < 4; i++)
#pragma unroll
      for (int rr = 0; rr < 4; rr++) {
        const int m = m0 + wm + i * 16 + fq * 4 + rr;
        C[(long)m * V_ + n] = acc[i][j][rr] + bv;
      }
  }
}

// ---------------- persistent GRU scan (R9 geometry, proven 316 us) ----------------
__global__ __launch_bounds__(256) void GG_scan_persist(
    __hip_bfloat16* __restrict__ hfull,       // [B][64][512]
    const __hip_bfloat16* __restrict__ gi,    // [M][G]
    const __hip_bfloat16* __restrict__ WhhB,  // [G][512] bf16
    const float* __restrict__ bhh,            // [G] f32
    int* __restrict__ flagbase) {
  __shared__ short sW[48 * 512];      // 49,152 B, persistent all 63 steps
  const int lane = threadIdx.x & 63;
  const int wave = threadIdx.x >> 6;
  const int strip = blockIdx.x & 31;
  const int half  = blockIdx.x >> 5;
  const int d0 = strip * 16;
  const int fr = lane & 15;
  const int g4 = lane >> 4;            // 0..3
  int* myflags = flagbase + half * 32;

  for (int rr = wave; rr < 48; rr += 4) {
    const int grow = (rr >> 4) * 512 + d0 + (rr & 15);
    gload_lds16(WhhB + (long)grow * 512 + (lane ^ (rr & 7)) * 8, sW + rr * 512);
  }

  const int dd = d0 + fr;
  const int bbase = half * 64 + wave * 16 + g4 * 4;
  const float br_ = bhh[dd], bz_ = bhh[512 + dd], bn_ = bhh[1024 + dd];
  const short* gis = (const short*)gi;

  const int arow = half * 64 + wave * 16 + fr;
  const ull_t abase0 =
      (ull_t)hfull + ((ull_t)arow * 64 * 512 + (unsigned)(g4 * 8)) * 2ull;

  ull_t sbase[4];
  const short* gp0[4];
#pragma unroll
  for (int rr = 0; rr < 4; rr++) {
    sbase[rr] = (ull_t)hfull +
                ((ull_t)(bbase + rr) * 64 * 512 + (unsigned)dd) * 2ull;
    gp0[rr] = gis + (long)(bbase + rr) * T_ * G_ + dd;
  }

  unsigned cr[4], cz[4], cn[4];
  float hp[4];
#pragma unroll
  for (int rr = 0; rr < 4; rr++) {
    cr[rr] = (unsigned short)gp0[rr][0];
    cz[rr] = (unsigned short)gp0[rr][512];
    cn[rr] = (unsigned short)gp0[rr][1024];
    hp[rr] = bf2f(*(const short*)&hfull[((long)(bbase + rr) * 64) * 512 + dd]);
  }

  asm volatile("s_waitcnt vmcnt(0)" ::: "memory");
  __syncthreads();  // sW fully staged

  for (int t = 0; t < T_; t++) {
    if (t > 0) {
      while (true) {
        const int v = __hip_atomic_load(&myflags[lane & 31], __ATOMIC_RELAXED,
                                        __HIP_MEMORY_SCOPE_SYSTEM);
        if (__all(v >= t)) break;
        __builtin_amdgcn_s_sleep(1);
      }
    }

    const ull_t ab = abase0 + (ull_t)t * 1024ull;
    f32x4_t a[16];
#define ALOAD(IDX, OFF)                                                        \
    asm volatile("global_load_dwordx4 %0, %1, off offset:" #OFF " sc0 sc1"     \
                 : "=v"(a[IDX]) : "v"(ab));
    ALOAD(0, 0)    ALOAD(1, 64)   ALOAD(2, 128)  ALOAD(3, 192)
    ALOAD(4, 256)  ALOAD(5, 320)  ALOAD(6, 384)  ALOAD(7, 448)
    ALOAD(8, 512)  ALOAD(9, 576)  ALOAD(10, 640) ALOAD(11, 704)
    ALOAD(12, 768) ALOAD(13, 832) ALOAD(14, 896) ALOAD(15, 960)
#undef ALOAD

    const int tp = (t < T_ - 1) ? (t + 1) : (T_ - 1);
    unsigned nr[4], nz[4], nn[4];
#pragma unroll
    for (int rr = 0; rr < 4; rr++) {
      const short* gp = gp0[rr] + (long)tp * G_;
      asm volatile("global_load_ushort %0, %1, off"             : "=v"(nr[rr]) : "v"(gp));
      asm volatile("global_load_ushort %0, %1, off offset:1024" : "=v"(nz[rr]) : "v"(gp));
      asm volatile("global_load_ushort %0, %1, off offset:2048" : "=v"(nn[rr]) : "v"(gp));
    }

    asm volatile("s_waitcnt vmcnt(12)" ::: "memory");
    __builtin_amdgcn_sched_barrier(0);

    f32x4_t acc[3] = {};
#pragma unroll
    for (int kt = 0; kt < 16; kt++) {
      const bf16x8_t afr = __builtin_bit_cast(bf16x8_t, a[kt]);
      const int gsw = ((kt * 4 + g4) ^ (fr & 7)) * 8;
      bf16x8_t bfr[3];
#pragma unroll
      for (int j = 0; j < 3; j++) bfr[j] = lds_frag(sW + (j * 16 + fr) * 512 + gsw);
#pragma unroll
      for (int j = 0; j < 3; j++)
        acc[j] = __builtin_amdgcn_mfma_f32_16x16x32_bf16(afr, bfr[j], acc[j], 0, 0, 0);
    }

#pragma unroll
    for (int rr = 0; rr < 4; rr++) {
      const float rg = sigmoidf_(bf2f((short)cr[rr]) + acc[0][rr] + br_);
      const float zg = sigmoidf_(bf2f((short)cz[rr]) + acc[1][rr] + bz_);
      const float ng = tanhf(bf2f((short)cn[rr]) + rg * (acc[2][rr] + bn_));
      const short hnb = f2bf((1.f - zg) * ng + zg * hp[rr]);
      hp[rr] = bf2f(hnb);
      const ull_t saddr = sbase[rr] + (ull_t)(t + 1) * 1024ull;
      const unsigned int val = (unsigned short)hnb;
      asm volatile("global_store_short %0, %1, off sc0 sc1"
                   :: "v"(saddr), "v"(val) : "memory");
    }

    asm volatile("s_waitcnt vmcnt(0)" ::: "memory");
    __builtin_amdgcn_sched_barrier(0);
#pragma unroll
    for (int rr = 0; rr < 4; rr++) { cr[rr] = nr[rr]; cz[rr] = nz[rr]; cn[rr] = nn[rr]; }

    if (t < T_ - 1) {
      __syncthreads();
      if (threadIdx.x == 0)
        __hip_atomic_store(&myflags[strip], t + 1, __ATOMIC_RELAXED,
                           __HIP_MEMORY_SCOPE_SYSTEM);
    }
  }
}

extern "C" void kernel_launch(void* const* d_in, const int* in_sizes, int n_in,
                              void* d_out, int out_size, void* d_ws, size_t ws_size,
                              hipStream_t stream) {
  const float* gf      = (const float*)d_in[0];
  const int*   cap     = (const int*)d_in[1];
  const int*   lens    = (const int*)d_in[2];
  const float* W_embed = (const float*)d_in[3];
  const float* W_init  = (const float*)d_in[4];
  const float* b_init  = (const float*)d_in[5];
  const float* W_ih    = (const float*)d_in[6];
  const float* W_hh    = (const float*)d_in[7];
  const float* b_ih    = (const float*)d_in[8];
  const float* b_hh    = (const float*)d_in[9];
  const float* W_fc    = (const float*)d_in[10];
  const float* b_fc    = (const float*)d_in[11];
  float* out = (float*)d_out;

  // d_out scratch (all consumed before the logits GEMM writes d_out):
  char* ob = (char*)d_out;
  __hip_bfloat16* gi_ws  = (__hip_bfloat16*)ob;               // [0, 24,772,608)
  __hip_bfloat16* WhhB   = (__hip_bfloat16*)(ob + 25165824);  // 1.5 MB
  __hip_bfloat16* WihB   = (__hip_bfloat16*)(ob + 27262976);  // 1.5 MB
  __hip_bfloat16* WembB  = (__hip_bfloat16*)(ob + 29360128);  // 10 MB
  __hip_bfloat16* WinitB = (__hip_bfloat16*)(ob + 40894464);  // 2 MB
  __hip_bfloat16* gfB    = (__hip_bfloat16*)(ob + 43253760);  // 0.5 MB

  // ws: hfull [B][64][512] bf16 + WfcB + flags
  __hip_bfloat16* hfull = (__hip_bfloat16*)d_ws;
  __hip_bfloat16* WfcB  = (__hip_bfloat16*)((char*)d_ws + 8388608);
  const bool big_ws = ws_size >= (size_t)(8388608 + 10240000 + 256);
  int* flags = (int*)((char*)d_ws + (big_ws ? 18628608 : 8388608));

  // 0. reset barrier flags
  hipMemsetAsync(flags, 0, 256, stream);

  // 1. all weight/input converts in ONE launch
  GG_cvt6<<<dim3(6408), 256, 0, stream>>>(W_hh, WhhB, W_ih, WihB, W_embed, WembB,
                                          W_init, WinitB, gf, gfB,
                                          W_fc, big_ws ? WfcB : nullptr);

  // 2. fused prep: h0 + gi + tail (761 blocks)
  GG_prep<<<dim3(761), 256, 0, stream>>>(gfB, WinitB, b_init, hfull,
                                         WembB, cap, WihB, b_ih, gi_ws, lens, out);

  // 3. GRU scan: 64 blocks, 2 groups of 32 (16-wide strips) — R9 proven
  GG_scan_persist<<<dim3(SCAN_NB), 256, 0, stream>>>(hfull, gi_ws, WhhB, b_hh, flags);

  // 4. logits: 128x256 tile, 8 waves, XCD-banded, T2-swizzled
  if (big_ws)
    GG_gemm_logits<true><<<dim3(2520), 512, 0, stream>>>(hfull, WfcB, b_fc, out);
  else
    GG_gemm_logits<false><<<dim3(2520), 512, 0, stream>>>(hfull, W_fc, b_fc, out);
}